// Round 10
// baseline (14615.887 us; speedup 1.0000x reference)
//
#include <hip/hip_runtime.h>
#include <stdint.h>

typedef unsigned short u16;
typedef unsigned int   u32;
typedef unsigned long long u64;
typedef __attribute__((ext_vector_type(4)))  int   i32x4;
typedef __attribute__((ext_vector_type(4)))  float f32x4;
typedef __attribute__((ext_vector_type(8)))  u16   u16x8;
typedef __attribute__((ext_vector_type(8)))  short s16x8;

typedef __attribute__((address_space(3))) char  as3_char;
typedef __attribute__((address_space(3))) i32x4 as3_i32x4;
typedef __attribute__((address_space(3))) s16x8 as3_s16x8;

#define B_    64
#define T_    512
#define DIN_  512
#define H_    1024
#define NBLK_ 256
#define NTHR_ 512

#define HN_BASE_  (64ull*512*1024)
#define CN_BASE_  (HN_BASE_ + 2ull*64*1024)

// ---- workspace layout (bytes) ----
#define WB0_OFF  0ull
#define WB0_SZ   (128ull*48*2048)         // 12.6 MB (NS=48)
#define WB1_OFF  (WB0_OFF + WB0_SZ)
#define WB1_SZ   (128ull*64*2048)         // 16.8 MB (NS=64)
#define RING_OFF (WB1_OFF + WB1_SZ)
#define RSLOT_   131072ull                // one [64][1024] bf16 h0 snapshot
#define RING_SZ  (513ull*RSLOT_)          // 67.2 MB: slot t+1 = h0[t]; slot 0 = zeros
#define BIAS_OFF (RING_OFF + RING_SZ)
#define SYNC_OFF (BIAS_OFF + 32768)       // 64 KB sync region

__device__ __forceinline__ u16 f2bf(float f) {   // RNE fp32 -> bf16
  u32 u = __builtin_bit_cast(u32, f);
  return (u16)((u + 0x7FFFu + ((u >> 16) & 1u)) >> 16);
}
__device__ __forceinline__ float sigf(float x) {
  float e = __builtin_amdgcn_exp2f(x * -1.442695041f);
  return __builtin_amdgcn_rcpf(1.0f + e);
}
__device__ __forceinline__ float tanhf_fast(float x) {
  float e = __builtin_amdgcn_exp2f(x * -2.885390082f);
  float r = __builtin_amdgcn_rcpf(1.0f + e);
  return fmaf(2.0f, r, -1.0f);
}

#define VMW(n)  asm volatile("s_waitcnt vmcnt(" #n ")" ::: "memory")

// ============================ prep kernels ============================

__global__ void prep_misc(const float* __restrict__ bih0, const float* __restrict__ bhh0,
                          const float* __restrict__ bih1, const float* __restrict__ bhh1,
                          float* __restrict__ bias, u32* __restrict__ ring0,
                          u32* __restrict__ sync)
{
  int i = blockIdx.x * 256 + threadIdx.x;
  if (i < 4096) bias[i] = bih0[i] + bhh0[i];
  else if (i < 8192) bias[i] = bih1[i - 4096] + bhh1[i - 4096];
  if (i < 32768) ring0[i] = 0u;                  // zero ring slot 0 (h0[-1] = 0)
  if (i < 16384) sync[i] = 0u;                   // zero sync region (64 KB)
}

// W[k][n] fp32 -> fragment-major bf16 per 32-col block (round-9 proven):
//   gate = n>>10, hcol = n&1023, j = hcol>>3, hl = hcol&7, cc = hl*4+gate,
//   nt = cc>>4, l15 = cc&15; k: jj = k>>5, lg = (k>>3)&3.
//   dest = Wb + j*(NS*2048) + (nt*NS+jj)*1024 + (lg*16+l15)*16.
__global__ void prep_w(const float* __restrict__ Wih0, const float* __restrict__ Whh0,
                       const float* __restrict__ Wih1, const float* __restrict__ Whh1,
                       u16* __restrict__ Wb0, u16* __restrict__ Wb1)
{
  __shared__ u16 tile[64][72];
  const int bid = blockIdx.x;
  const int layer = (bid >= 1536) ? 1 : 0;
  const int lb = layer ? bid - 1536 : bid;
  const int nkt = layer ? 32 : 24;
  const int kt = lb % nkt, nt_ = lb / nkt;
  const int K = layer ? 2048 : 1536;
  const int NS = K >> 5;
  const int xlen = layer ? 1024 : 512;
  const float* Wih = layer ? Wih1 : Wih0;
  const float* Whh = layer ? Whh1 : Whh0;
  char* Wb = (char*)(layer ? Wb1 : Wb0);
  const int k0 = kt * 64, n0 = nt_ * 64;
  const int t = threadIdx.x;
  {
    int kr = t >> 2, ncs = (t & 3) * 16;
    int kk = k0 + kr;
    const float* src = (kk < xlen) ? (Wih + (size_t)kk * 4096)
                                   : (Whh + (size_t)(kk - xlen) * 4096);
    const float* p = src + n0 + ncs;
#pragma unroll
    for (int v = 0; v < 4; ++v) {
      f32x4 f = *(const f32x4*)(p + v * 4);
#pragma unroll
      for (int e = 0; e < 4; ++e) tile[kr][ncs + v*4 + e] = f2bf(f[e]);
    }
  }
  __syncthreads();
  {
    int c2 = t >> 2;
    int n = n0 + c2;
    int gate = n >> 10, hcol = n & 1023;
    int j = hcol >> 3, hl = hcol & 7;
    int cc = hl * 4 + gate;
    int ntile = cc >> 4, l15 = cc & 15;
    char* base = Wb + (size_t)j * ((size_t)NS * 2048);
#pragma unroll
    for (int kv = 0; kv < 2; ++kv) {
      int k8 = (t & 3) + 4 * kv;
      int jj = (k0 >> 5) + (k8 >> 2);
      int lg = k8 & 3;
      size_t off = (size_t)(ntile * NS + jj) * 1024 + (size_t)(lg * 16 + l15) * 16;
      u16x8 vv;
#pragma unroll
      for (int e = 0; e < 8; ++e) vv[e] = tile[k8*8 + e][c2];
      *(u16x8*)(base + off) = vv;
    }
  }
}

// ============================ persistent LSTM kernel ============================
// Round-9 skeleton (weights-in-LDS, 513-slot ring, plain cached A reads, pure
// intrinsic MFMA) + two changes:
//  1. A-loads in 8-fragment BURSTS with 1-burst-ahead prefetch (kills the 64-deep
//     serial load-latency chain; all indices compile-time).
//  2. RMW-free flag barrier: block stores arrival to own 128B-spaced slot;
//     block 0 polls all 256 slots in parallel (threads 0..255), then one global
//     flag. No serialized atomic RMWs.

template<int LAYER>
__device__ __forceinline__ void phase(
    const int t, const int tid, const int j,
    const float* __restrict__ x, const char* __restrict__ ring,
    float* __restrict__ out,
    const float b0, const float b1, const float b2, const float b3,
    const int colg, float& cst, as3_char* wLds, float* gatesL)
{
  constexpr int K  = LAYER ? 2048 : 1536;
  constexpr int NS = K / 32;
  constexpr int NB = NS / 8;                // bursts of 8 fragments
  const int lane = tid & 63, w = tid >> 6;
  const int m = w >> 1, ntile = w & 1;
  const int l15 = lane & 15, lg = lane >> 4;
  const int arow = m * 16 + l15;
  const as3_char* bbase = wLds + (size_t)(ntile * NS) * 1024 + (size_t)lane * 16;

  const u16* h0r = (const u16*)(ring + (size_t)t * RSLOT_);          // h0[t-1]
  const u16* h0n = (const u16*)(ring + (size_t)(t + 1) * RSLOT_);    // h0[t]

  auto LOADF = [&](int jj) -> s16x8 {
    if (LAYER == 0) {
      if (jj < 16) {                        // x part: fp32 -> bf16 inline
        const float* xp = x + ((size_t)arow * T_ + t) * DIN_ + jj * 32 + lg * 8;
        f32x4 u = *(const f32x4*)xp;
        f32x4 v = *(const f32x4*)(xp + 4);
        u16x8 p;
#pragma unroll
        for (int e = 0; e < 4; ++e) { p[e] = f2bf(u[e]); p[4+e] = f2bf(v[e]); }
        return __builtin_bit_cast(s16x8, p);
      }
      return *(const s16x8*)(h0r + (size_t)arow * H_ + (jj - 16) * 32 + lg * 8);
    } else {
      if (jj < 32)
        return *(const s16x8*)(h0n + (size_t)arow * H_ + jj * 32 + lg * 8);
      if (t >= 1) {                         // h1[t-1] from out (fp32)
        const float* op = out + ((size_t)arow * T_ + (t - 1)) * H_ + (jj - 32) * 32 + lg * 8;
        f32x4 u = *(const f32x4*)op;
        f32x4 v = *(const f32x4*)(op + 4);
        u16x8 p;
#pragma unroll
        for (int e = 0; e < 4; ++e) { p[e] = f2bf(u[e]); p[4+e] = f2bf(v[e]); }
        return __builtin_bit_cast(s16x8, p);
      }
      return s16x8{0,0,0,0,0,0,0,0};
    }
  };

  f32x4 ac0 = {}, ac1 = {};
  s16x8 f[2][8];
#pragma unroll
  for (int i = 0; i < 8; ++i) f[0][i] = LOADF(i);
#pragma unroll
  for (int b = 0; b < NB; ++b) {
    if (b + 1 < NB) {
#pragma unroll
      for (int i = 0; i < 8; ++i) f[(b + 1) & 1][i] = LOADF((b + 1) * 8 + i);
    }
#pragma unroll
    for (int i = 0; i < 8; ++i) {
      s16x8 bv = *(const as3_s16x8*)(bbase + (size_t)(b * 8 + i) * 1024);
      if (i & 1) ac1 = __builtin_amdgcn_mfma_f32_16x16x32_bf16(f[b & 1][i], bv, ac1, 0, 0, 0);
      else       ac0 = __builtin_amdgcn_mfma_f32_16x16x32_bf16(f[b & 1][i], bv, ac0, 0, 0, 0);
    }
  }
  f32x4 acc = ac0 + ac1;

  // ---- gates exchange: gatesL[cc(32)][row(64+4 pad)] (round-9 proven) ----
  *(f32x4*)(gatesL + (size_t)(ntile * 16 + l15) * 68 + m * 16 + lg * 4) = acc;
  __syncthreads();

  // ---- cell update: thread = (erow = tid>>3, ehl = tid&7) ----
  {
    const int erow = tid >> 3, ehl = tid & 7;
    float g0 = gatesL[(size_t)(ehl * 4 + 0) * 68 + erow];
    float g1 = gatesL[(size_t)(ehl * 4 + 1) * 68 + erow];
    float g2 = gatesL[(size_t)(ehl * 4 + 2) * 68 + erow];
    float g3 = gatesL[(size_t)(ehl * 4 + 3) * 68 + erow];
    float ig = sigf(g0 + b0);
    float fg = sigf(g1 + b1);
    float cg = fmaxf(g2 + b2, 0.0f);
    float og = sigf(g3 + b3);
    float cn = fg * cst + ig * cg;
    cst = cn;
    float h = og * tanhf_fast(cn);
    if (LAYER == 0) {                       // h0[t] -> ring slot t+1 (sc0sc1)
      u32 hb = (u32)f2bf(h);
      u64 a = (u64)(ring + (size_t)(t + 1) * RSLOT_ + ((size_t)erow * H_ + colg) * 2);
      asm volatile("global_store_short %0, %1, off sc0 sc1" :: "v"(a), "v"(hb) : "memory");
    } else {                                // out[b][t][h] fp32 (sc0sc1)
      u64 a = (u64)((char*)out + (((size_t)erow * T_ + t) * H_ + colg) * 4);
      asm volatile("global_store_dword %0, %1, off sc0 sc1" :: "v"(a), "v"(h) : "memory");
    }
    if (t == T_ - 1) {
      out[HN_BASE_ + ((size_t)LAYER * 64 + erow) * H_ + colg] = h;
      out[CN_BASE_ + ((size_t)LAYER * 64 + erow) * H_ + colg] = cn;
    }
  }
}

__global__ __launch_bounds__(NTHR_, 1) void lstm_persist(
    const float* __restrict__ x, const u16* __restrict__ Wb0, const u16* __restrict__ Wb1,
    char* __restrict__ ring, const float* __restrict__ bias,
    u32* __restrict__ sync, float* __restrict__ out)
{
  __shared__ __align__(16) char wLdsRaw[131072];       // weights slice (96/128 KB)
  __shared__ __align__(16) float gatesL[32 * 68];      // 8.7 KB
  as3_char* wLds = (as3_char*)wLdsRaw;
  const int tid = threadIdx.x;
  const int bid = blockIdx.x;
  const int layer = bid >> 7, j = bid & 127;
  const int NSl = layer ? 64 : 48;
  const char* wbg = layer ? ((const char*)Wb1 + (size_t)j * ((size_t)64 * 2048))
                          : ((const char*)Wb0 + (size_t)j * ((size_t)48 * 2048));

  // ---- one-time: load weight slice into LDS ----
  for (int off = tid * 16; off < NSl * 2048; off += NTHR_ * 16)
    *(as3_i32x4*)(wLds + off) = *(const i32x4*)(wbg + off);
  __syncthreads();

  const int ehl = tid & 7;
  const int colg = j * 8 + ehl;
  float b0, b1, b2, b3;
  {
    const float* bb = bias + layer * 4096;
    b0 = bb[colg]; b1 = bb[1024 + colg]; b2 = bb[2048 + colg]; b3 = bb[3072 + colg];
  }
  float cst = 0.f;
  u32* gflag = sync + 8192;

  for (int s = 0; s <= T_; ++s) {
    if (layer == 0) {
      if (s < T_)
        phase<0>(s, tid, j, x, ring, out, b0, b1, b2, b3, colg, cst, wLds, gatesL);
    } else {
      if (s >= 1)
        phase<1>(s - 1, tid, j, x, ring, out, b0, b1, b2, b3, colg, cst, wLds, gatesL);
    }
    // ---- RMW-free flag barrier ----
    VMW(0);                                  // drain data stores (incl. sc0sc1)
    __syncthreads();
    if (tid == 0)
      __hip_atomic_store(sync + (size_t)bid * 32, (u32)(s + 1),
                         __ATOMIC_RELAXED, __HIP_MEMORY_SCOPE_AGENT);
    if (bid == 0) {
      if (tid < 256) {
        while (__hip_atomic_load(sync + (size_t)tid * 32,
                                 __ATOMIC_RELAXED, __HIP_MEMORY_SCOPE_AGENT) < (u32)(s + 1))
          __builtin_amdgcn_s_sleep(1);
      }
      __syncthreads();
      if (tid == 0)
        __hip_atomic_store(gflag, (u32)(s + 1),
                           __ATOMIC_RELAXED, __HIP_MEMORY_SCOPE_AGENT);
    } else {
      if (tid == 0) {
        while (__hip_atomic_load(gflag, __ATOMIC_RELAXED,
                                 __HIP_MEMORY_SCOPE_AGENT) < (u32)(s + 1))
          __builtin_amdgcn_s_sleep(1);
      }
      __syncthreads();
    }
  }
}

// ============================ host launch ============================

extern "C" void kernel_launch(void* const* d_in, const int* in_sizes, int n_in,
                              void* d_out, int out_size, void* d_ws, size_t ws_size,
                              hipStream_t stream)
{
  const float* x    = (const float*)d_in[0];
  const float* Wih0 = (const float*)d_in[1];
  const float* bih0 = (const float*)d_in[2];
  const float* Whh0 = (const float*)d_in[3];
  const float* bhh0 = (const float*)d_in[4];
  const float* Wih1 = (const float*)d_in[5];
  const float* bih1 = (const float*)d_in[6];
  const float* Whh1 = (const float*)d_in[7];
  const float* bhh1 = (const float*)d_in[8];

  char* ws = (char*)d_ws;
  u16* Wb0    = (u16*)(ws + WB0_OFF);
  u16* Wb1    = (u16*)(ws + WB1_OFF);
  char* ring  = ws + RING_OFF;
  float* bias = (float*)(ws + BIAS_OFF);
  u32* sync   = (u32*)(ws + SYNC_OFF);
  float* out  = (float*)d_out;

  prep_misc<<<1024, 256, 0, stream>>>(bih0, bhh0, bih1, bhh1, bias, (u32*)ring, sync);
  prep_w<<<3584, 256, 0, stream>>>(Wih0, Whh0, Wih1, Whh1, Wb0, Wb1);
  lstm_persist<<<NBLK_, NTHR_, 0, stream>>>(x, Wb0, Wb1, ring, bias, sync, out);
}

// Round 11
// 9160.819 us; speedup vs baseline: 1.5955x; 1.5955x over previous
//
#include <hip/hip_runtime.h>
#include <stdint.h>

typedef unsigned short u16;
typedef unsigned int   u32;
typedef unsigned long long u64;
typedef __attribute__((ext_vector_type(4)))  int   i32x4;
typedef __attribute__((ext_vector_type(4)))  float f32x4;
typedef __attribute__((ext_vector_type(8)))  u16   u16x8;
typedef __attribute__((ext_vector_type(8)))  short s16x8;

typedef __attribute__((address_space(3))) char  as3_char;
typedef __attribute__((address_space(3))) i32x4 as3_i32x4;
typedef __attribute__((address_space(3))) s16x8 as3_s16x8;

#define B_    64
#define T_    512
#define DIN_  512
#define H_    1024
#define NBLK_ 256
#define NTHR_ 512

#define HN_BASE_  (64ull*512*1024)
#define CN_BASE_  (HN_BASE_ + 2ull*64*1024)

// ---- workspace layout (bytes) ----
#define WB0_OFF   0ull
#define WB0_SZ    (64ull*64*1536*2)        // 12.6 MB [grp][cd][K]
#define WB1_OFF   (WB0_OFF + WB0_SZ)
#define WB1_SZ    (64ull*64*2048*2)        // 16.8 MB
#define RSLOT_    131072ull                // one [64][1024] bf16 h snapshot
#define NRING_    257
#define RING0_OFF (WB1_OFF + WB1_SZ)
#define RING1_OFF (RING0_OFF + NRING_*RSLOT_)
#define BIAS_OFF  (RING1_OFF + NRING_*RSLOT_)
#define SYNC_OFF  (BIAS_OFF + 32768)       // 64 KB sync region
// total ~96.8 MB (== round-9 proven budget)

__device__ __forceinline__ u16 f2bf(float f) {   // RNE fp32 -> bf16
  u32 u = __builtin_bit_cast(u32, f);
  return (u16)((u + 0x7FFFu + ((u >> 16) & 1u)) >> 16);
}
__device__ __forceinline__ float sigf(float x) {
  float e = __builtin_amdgcn_exp2f(x * -1.442695041f);
  return __builtin_amdgcn_rcpf(1.0f + e);
}
__device__ __forceinline__ float tanhf_fast(float x) {
  float e = __builtin_amdgcn_exp2f(x * -2.885390082f);
  float r = __builtin_amdgcn_rcpf(1.0f + e);
  return fmaf(2.0f, r, -1.0f);
}

#define VMW(n)  asm volatile("s_waitcnt vmcnt(" #n ")" ::: "memory")

// ============================ prep kernels ============================

__global__ void prep_misc(const float* __restrict__ bih0, const float* __restrict__ bhh0,
                          const float* __restrict__ bih1, const float* __restrict__ bhh1,
                          float* __restrict__ bias, u32* __restrict__ r0z,
                          u32* __restrict__ r1z, u32* __restrict__ sync)
{
  int i = blockIdx.x * 256 + threadIdx.x;        // 1024*256 = 262144 threads
  if (i < 4096) bias[i] = bih0[i] + bhh0[i];
  else if (i < 8192) bias[i] = bih1[i - 4096] + bhh1[i - 4096];
  if (i < 32768) { r0z[i] = 0u; r1z[i] = 0u; }   // zero ring slot 0 (h[-1]=0)
  if (i < 16384) sync[i] = 0u;
}

// W[k][n] fp32 -> Wb[grp][cd][K] bf16, grp=hcol>>4 (64 groups of 16 h-cols),
// cd = gate*16 + (hcol&15).  (round-1/2/6 proven version)
__global__ void prep_w(const float* __restrict__ Wih0, const float* __restrict__ Whh0,
                       const float* __restrict__ Wih1, const float* __restrict__ Whh1,
                       u16* __restrict__ Wb0, u16* __restrict__ Wb1)
{
  __shared__ u16 tile[64][72];
  const int bid = blockIdx.x;
  const int layer = (bid >= 1536) ? 1 : 0;
  const int lb = layer ? bid - 1536 : bid;
  const int nkt = layer ? 32 : 24;
  const int kt = lb % nkt, nt = lb / nkt;
  const int K = layer ? 2048 : 1536;
  const int xlen = layer ? 1024 : 512;
  const float* Wih = layer ? Wih1 : Wih0;
  const float* Whh = layer ? Whh1 : Whh0;
  u16* Wb = layer ? Wb1 : Wb0;
  const int k0 = kt * 64, n0 = nt * 64;
  const int t = threadIdx.x;
  {
    int kr = t >> 2, ncs = (t & 3) * 16;
    int kk = k0 + kr;
    const float* src = (kk < xlen) ? (Wih + (size_t)kk * 4096)
                                   : (Whh + (size_t)(kk - xlen) * 4096);
    const float* p = src + n0 + ncs;
#pragma unroll
    for (int v = 0; v < 4; ++v) {
      f32x4 f = *(const f32x4*)(p + v * 4);
#pragma unroll
      for (int e = 0; e < 4; ++e) tile[kr][ncs + v*4 + e] = f2bf(f[e]);
    }
  }
  __syncthreads();
  {
    int c = t >> 2;
    int n = n0 + c;
    int gate = n >> 10, hcol = n & 1023;
    int grp = hcol >> 4, cd = gate * 16 + (hcol & 15);
    u16* dstc = Wb + ((size_t)(grp * 64 + cd) * K + k0);
#pragma unroll
    for (int kv = 0; kv < 2; ++kv) {
      int k8 = (t & 3) + 4 * kv;
      u16x8 vv;
#pragma unroll
      for (int e = 0; e < 8; ++e) vv[e] = tile[k8*8 + e][c];
      *(u16x8*)(dstc + k8 * 8) = vv;
    }
  }
}

// ============================ persistent LSTM kernel ============================
// Round-6 geometry (PROVEN best): 256 blocks = layer(2) x rowhalf(2) x j(64 col-
// groups of 16 h-cols); XCD = j%8 -> per-XCD weights 3.67 MB L2-resident.
// NEW vs round 6: h0/h1 live in 257-slot RINGS -- written sc0sc1 (LLC), read with
// PLAIN cached loads (fresh address per step; first reader per XCD fills L2, the
// other blocks hit XCD-local L2). Converts 12.5 MB/step of LLC-latency reads
// into ~3 MB/step of unique fills + L2-speed broadcast. x read fp32 directly
// (64 KB/block), cvt during staging. out written plain (no on-device reader).
// A staged to LDS: issue-all -> vmcnt(0) -> LDS (round-5 proven). GEMM: wave
// w=(m=w>>2,n=w&3) owns one 16x16 C-tile, pure intrinsic mfma_16x16x32_bf16.
// Round-10 flag barrier (no RMW).

template<int LAYER>
__device__ __forceinline__ void phase(
    const int t, const int i32b, const int tid,
    const float* __restrict__ x,
    const char* __restrict__ wb,
    const char* __restrict__ rdH0, const char* __restrict__ rdH1,
    char* __restrict__ wrH,
    const float b0, const float b1, const float b2, const float b3,
    const int colg, float& cst,
    float* __restrict__ out, as3_char* ldsA, float* gatesL)
{
  constexpr int K  = LAYER ? 2048 : 1536;
  constexpr int RS = K * 2 + 32;           // padded LDS row stride (bytes)
  constexpr int NS = K / 32;               // k32 slices
  const int lane = tid & 63, w = tid >> 6;
  const int l15 = lane & 15, lg = lane >> 4;
  const int wm = w >> 2, wn = w & 3;

  // ---- stage A [32 rows x K] to LDS: issue ALL plain loads, vmcnt(0), write ----
  if (LAYER == 0) {
    i32x4 sh[8]; int dsh[8];
    f32x4 xu[4], xv[4]; int dsx[4];
#pragma unroll
    for (int c = 0; c < 8; ++c) {          // h0 part: k 512..1535 (bf16)
      int ch = c * 512 + tid;
      int row = ch >> 7, k8 = ch & 127;
      sh[c] = *(const i32x4*)(rdH0 + ((size_t)(i32b + row) * H_ + k8 * 8) * 2);
      dsh[c] = row * RS + (64 + k8) * 16;
    }
#pragma unroll
    for (int c = 0; c < 4; ++c) {          // x part: k 0..511 (fp32 -> bf16)
      int ch = c * 512 + tid;
      int row = ch >> 6, k8 = ch & 63;
      const float* xp = x + ((size_t)(i32b + row) * T_ + t) * DIN_ + k8 * 8;
      xu[c] = *(const f32x4*)xp;
      xv[c] = *(const f32x4*)(xp + 4);
      dsx[c] = row * RS + k8 * 16;
    }
    VMW(0);
    __builtin_amdgcn_sched_barrier(0);
#pragma unroll
    for (int c = 0; c < 8; ++c) *(as3_i32x4*)(ldsA + dsh[c]) = sh[c];
#pragma unroll
    for (int c = 0; c < 4; ++c) {
      u16x8 p;
#pragma unroll
      for (int e = 0; e < 4; ++e) { p[e] = f2bf(xu[c][e]); p[4+e] = f2bf(xv[c][e]); }
      *(as3_i32x4*)(ldsA + dsx[c]) = __builtin_bit_cast(i32x4, p);
    }
  } else {
    i32x4 sh[16]; int dsd[16];
#pragma unroll
    for (int c = 0; c < 8; ++c) {          // h0[t] part: k 0..1023
      int ch = c * 512 + tid;
      int row = ch >> 7, k8 = ch & 127;
      sh[c] = *(const i32x4*)(rdH0 + ((size_t)(i32b + row) * H_ + k8 * 8) * 2);
      dsd[c] = row * RS + k8 * 16;
    }
#pragma unroll
    for (int c = 0; c < 8; ++c) {          // h1[t-1] part: k 1024..2047
      int ch = c * 512 + tid;
      int row = ch >> 7, k8 = ch & 127;
      sh[8 + c] = *(const i32x4*)(rdH1 + ((size_t)(i32b + row) * H_ + k8 * 8) * 2);
      dsd[8 + c] = row * RS + (128 + k8) * 16;
    }
    VMW(0);
    __builtin_amdgcn_sched_barrier(0);
#pragma unroll
    for (int c = 0; c < 16; ++c) *(as3_i32x4*)(ldsA + dsd[c]) = sh[c];
  }
  __syncthreads();

  // ---- GEMM: one 16x16 tile per wave, full K, 2 interleaved accumulators ----
  f32x4 ac0 = {}, ac1 = {};
  const as3_char* arow = ldsA + (size_t)(wm * 16 + l15) * RS;
  const char* bbase = wb + (((size_t)(wn * 16 + l15)) * K + lg * 8) * 2;
#pragma unroll
  for (int jj = 0; jj < NS; jj += 2) {
    s16x8 a0 = *(const as3_s16x8*)(arow + jj * 64 + lg * 16);
    s16x8 a1 = *(const as3_s16x8*)(arow + (jj + 1) * 64 + lg * 16);
    s16x8 bv0 = *(const s16x8*)(bbase + jj * 64);
    s16x8 bv1 = *(const s16x8*)(bbase + (jj + 1) * 64);
    ac0 = __builtin_amdgcn_mfma_f32_16x16x32_bf16(a0, bv0, ac0, 0, 0, 0);
    ac1 = __builtin_amdgcn_mfma_f32_16x16x32_bf16(a1, bv1, ac1, 0, 0, 0);
  }
  f32x4 acc = ac0 + ac1;

  // ---- gates exchange: gatesL[cd(64)][row(36 pad)] fp32 (round-6 proven) ----
  *(f32x4*)(gatesL + (size_t)(wn * 16 + l15) * 36 + wm * 16 + lg * 4) = acc;
  __syncthreads();

  // ---- cell update: thread = (hc=tid&15, row=tid>>4), 1 c-elem/thread ----
  {
    const int hc = tid & 15, row = tid >> 4;
    float g0 = gatesL[(size_t)(0 * 16 + hc) * 36 + row];
    float g1 = gatesL[(size_t)(1 * 16 + hc) * 36 + row];
    float g2 = gatesL[(size_t)(2 * 16 + hc) * 36 + row];
    float g3 = gatesL[(size_t)(3 * 16 + hc) * 36 + row];
    float ig = sigf(g0 + b0);
    float fg = sigf(g1 + b1);
    float cg = fmaxf(g2 + b2, 0.0f);
    float og = sigf(g3 + b3);
    float cn = fg * cst + ig * cg;
    cst = cn;
    float h = og * tanhf_fast(cn);
    u32 hb = (u32)f2bf(h);
    int rowg = i32b + row;
    u64 a0 = (u64)(wrH + ((size_t)rowg * H_ + colg) * 2);
    asm volatile("global_store_short %0, %1, off sc0 sc1" :: "v"(a0), "v"(hb) : "memory");
    if (LAYER == 1) out[((size_t)rowg * T_ + t) * H_ + colg] = h;
    if (t == T_ - 1) {
      out[HN_BASE_ + ((size_t)LAYER * 64 + rowg) * H_ + colg] = h;
      out[CN_BASE_ + ((size_t)LAYER * 64 + rowg) * H_ + colg] = cn;
    }
  }
}

__global__ __launch_bounds__(NTHR_, 1) void lstm_persist(
    const float* __restrict__ x, const u16* __restrict__ Wb0, const u16* __restrict__ Wb1,
    char* __restrict__ ring0, char* __restrict__ ring1, const float* __restrict__ bias,
    u32* __restrict__ sync, float* __restrict__ out)
{
  __shared__ __align__(16) char ldsAraw[32 * (2048 * 2 + 32)];   // 132 KB (max layer)
  __shared__ __align__(16) float gatesL[64 * 36];
  as3_char* ldsA = (as3_char*)ldsAraw;
  const int tid = threadIdx.x;
  const int bid = blockIdx.x;
  const int layer = bid >> 7, i = (bid >> 6) & 1, j = bid & 63;
  const int i32b = i * 32;
  const char* wb = layer ? ((const char*)Wb1 + (size_t)j * 64 * 2048 * 2)
                         : ((const char*)Wb0 + (size_t)j * 64 * 1536 * 2);
  const int colg = j * 16 + (tid & 15);
  float b0, b1, b2, b3;
  {
    const float* bb = bias + layer * 4096;
    b0 = bb[colg]; b1 = bb[1024 + colg]; b2 = bb[2048 + colg]; b3 = bb[3072 + colg];
  }
  float cst = 0.f;
  u32* gflag = sync + 8192;

  for (int s = 0; s <= T_; ++s) {
    const int m0 = s % NRING_;
    const int m1 = (s + 1) % NRING_;
    const int mm = (s >= 1) ? (s - 1) % NRING_ : 0;
    if (layer == 0) {
      if (s < T_)
        phase<0>(s, i32b, tid, x, wb,
                 ring0 + (size_t)m0 * RSLOT_, nullptr,
                 ring0 + (size_t)m1 * RSLOT_,
                 b0, b1, b2, b3, colg, cst, out, ldsA, gatesL);
    } else {
      if (s >= 1)
        phase<1>(s - 1, i32b, tid, x, wb,
                 ring0 + (size_t)m0 * RSLOT_, ring1 + (size_t)mm * RSLOT_,
                 ring1 + (size_t)m0 * RSLOT_,
                 b0, b1, b2, b3, colg, cst, out, ldsA, gatesL);
    }
    // ---- RMW-free flag barrier (round-10 proven) ----
    VMW(0);
    __syncthreads();
    if (tid == 0)
      __hip_atomic_store(sync + (size_t)bid * 32, (u32)(s + 1),
                         __ATOMIC_RELAXED, __HIP_MEMORY_SCOPE_AGENT);
    if (bid == 0) {
      if (tid < 256) {
        while (__hip_atomic_load(sync + (size_t)tid * 32,
                                 __ATOMIC_RELAXED, __HIP_MEMORY_SCOPE_AGENT) < (u32)(s + 1))
          __builtin_amdgcn_s_sleep(1);
      }
      __syncthreads();
      if (tid == 0)
        __hip_atomic_store(gflag, (u32)(s + 1),
                           __ATOMIC_RELAXED, __HIP_MEMORY_SCOPE_AGENT);
    } else {
      if (tid == 0) {
        while (__hip_atomic_load(gflag, __ATOMIC_RELAXED,
                                 __HIP_MEMORY_SCOPE_AGENT) < (u32)(s + 1))
          __builtin_amdgcn_s_sleep(1);
      }
      __syncthreads();
    }
  }
}

// ============================ host launch ============================

extern "C" void kernel_launch(void* const* d_in, const int* in_sizes, int n_in,
                              void* d_out, int out_size, void* d_ws, size_t ws_size,
                              hipStream_t stream)
{
  const float* x    = (const float*)d_in[0];
  const float* Wih0 = (const float*)d_in[1];
  const float* bih0 = (const float*)d_in[2];
  const float* Whh0 = (const float*)d_in[3];
  const float* bhh0 = (const float*)d_in[4];
  const float* Wih1 = (const float*)d_in[5];
  const float* bih1 = (const float*)d_in[6];
  const float* Whh1 = (const float*)d_in[7];
  const float* bhh1 = (const float*)d_in[8];

  char* ws = (char*)d_ws;
  u16* Wb0    = (u16*)(ws + WB0_OFF);
  u16* Wb1    = (u16*)(ws + WB1_OFF);
  char* ring0 = ws + RING0_OFF;
  char* ring1 = ws + RING1_OFF;
  float* bias = (float*)(ws + BIAS_OFF);
  u32* sync   = (u32*)(ws + SYNC_OFF);
  float* out  = (float*)d_out;

  prep_misc<<<1024, 256, 0, stream>>>(bih0, bhh0, bih1, bhh1, bias,
                                      (u32*)ring0, (u32*)ring1, sync);
  prep_w<<<3584, 256, 0, stream>>>(Wih0, Whh0, Wih1, Whh1, Wb0, Wb1);
  lstm_persist<<<NBLK_, NTHR_, 0, stream>>>(x, Wb0, Wb1, ring0, ring1, bias, sync, out);
}